// Round 8
// baseline (1186.407 us; speedup 1.0000x reference)
//
#include <hip/hip_runtime.h>
#include <hip/hip_bf16.h>

#define D 128
#define LDK 136  // padded LDS row: 136 bf16 = 272B (row stride 68 dwords -> spreads banks)

typedef __bf16 bf16x8 __attribute__((ext_vector_type(8)));
typedef float  f32x4  __attribute__((ext_vector_type(4)));
typedef unsigned int u32x4 __attribute__((ext_vector_type(4)));
typedef unsigned short u16;

// fp32 -> bf16 round-to-nearest-even
__device__ __forceinline__ u16 f2bf(float f) {
    unsigned int u = __builtin_bit_cast(unsigned int, f);
    u = u + 0x7FFFu + ((u >> 16) & 1u);
    return (u16)(u >> 16);
}
__device__ __forceinline__ float bf2f(u16 h) {
    unsigned int u = ((unsigned int)h) << 16;
    return __builtin_bit_cast(float, u);
}
__device__ __forceinline__ unsigned int pk2(float lo, float hi) {
    return (unsigned int)f2bf(lo) | ((unsigned int)f2bf(hi) << 16);
}
__device__ __forceinline__ void cvt_store8(u16* dst, float4 a, float4 b) {
    uint4 v;
    v.x = pk2(a.x, a.y); v.y = pk2(a.z, a.w);
    v.z = pk2(b.x, b.y); v.w = pk2(b.z, b.w);
    *reinterpret_cast<uint4*>(dst) = v;
}
__device__ __forceinline__ void cvt_store8v(u16* dst, f32x4 a, f32x4 b) {
    uint4 v;
    v.x = pk2(a.x, a.y); v.y = pk2(a.z, a.w);
    v.z = pk2(b.x, b.y); v.w = pk2(b.z, b.w);
    *reinterpret_cast<uint4*>(dst) = v;
}
__device__ __forceinline__ bf16x8 cvt8r(f32x4 a, f32x4 b) {
    u32x4 v;
    v.x = pk2(a.x, a.y); v.y = pk2(a.z, a.w);
    v.z = pk2(b.x, b.y); v.w = pk2(b.z, b.w);
    return __builtin_bit_cast(bf16x8, v);
}

// ======== sort machinery: counting sort of edges by dst ========
__global__ __launch_bounds__(256)
void hist_kernel(const int* __restrict__ ei, int* __restrict__ counts, int E) {
    int e = blockIdx.x * 256 + threadIdx.x;
    if (e < E) atomicAdd(&counts[ei[E + e]], 1);
}

// --- coalesced 3-pass scan over cnt_elems (multiple of 1024) ---
__global__ __launch_bounds__(256)
void scan_partial(const int* __restrict__ counts, int* __restrict__ bsum) {
    const int b = blockIdx.x, t = threadIdx.x;
    const int4 v = reinterpret_cast<const int4*>(counts + (size_t)b * 1024)[t];
    int s = v.x + v.y + v.z + v.w;
    #pragma unroll
    for (int off = 1; off < 64; off <<= 1) s += __shfl_xor(s, off);
    __shared__ int ws[4];
    if ((t & 63) == 0) ws[t >> 6] = s;
    __syncthreads();
    if (t == 0) bsum[b] = ws[0] + ws[1] + ws[2] + ws[3];
}
__global__ __launch_bounds__(256)
void scan_bsum(int* __restrict__ bsum, int nb) {
    const int t = threadIdx.x;
    int s = (t < nb) ? bsum[t] : 0;
    int inc = s;
    const int lane = t & 63;
    #pragma unroll
    for (int off = 1; off < 64; off <<= 1) {
        int v = __shfl_up(inc, off);
        if (lane >= off) inc += v;
    }
    __shared__ int ws[4];
    if (lane == 63) ws[t >> 6] = inc;
    __syncthreads();
    int woff = 0;
    for (int i = 0; i < (t >> 6); ++i) woff += ws[i];
    if (t < nb) bsum[t] = woff + inc - s;
}
__global__ __launch_bounds__(256)
void scan_emit(const int* __restrict__ counts, const int* __restrict__ bsum,
               int* __restrict__ offsets) {
    const int b = blockIdx.x, t = threadIdx.x;
    const int4 v = reinterpret_cast<const int4*>(counts + (size_t)b * 1024)[t];
    const int s = v.x + v.y + v.z + v.w;
    int inc = s;
    const int lane = t & 63;
    #pragma unroll
    for (int off = 1; off < 64; off <<= 1) {
        int u = __shfl_up(inc, off);
        if (lane >= off) inc += u;
    }
    __shared__ int ws[4];
    if (lane == 63) ws[t >> 6] = inc;
    __syncthreads();
    int woff = bsum[b];
    for (int i = 0; i < (t >> 6); ++i) woff += ws[i];
    int e0 = woff + inc - s;
    int4 o;
    o.x = e0; o.y = e0 + v.x; o.z = o.y + v.y; o.w = o.z + v.z;
    reinterpret_cast<int4*>(offsets + (size_t)b * 1024)[t] = o;
}

// ======== scatter+permute: place (src,dst) record AND bf16 ea payload at sorted position
// Reads ea coalesced (edge order); random-WRITES 256B bf16 rows (fire-and-forget).
__global__ __launch_bounds__(256)
void scatter_permute(const int* __restrict__ ei, int* __restrict__ off,
                     const float* __restrict__ ea,
                     int2* __restrict__ rec2, u16* __restrict__ ea_s, int E) {
    __shared__ int p_lds[128];
    const int tid = threadIdx.x;
    const int e0  = blockIdx.x * 128;
    if (tid < 128) {
        const int e = e0 + tid;
        if (e < E) {
            const int s = ei[e];
            const int d = ei[E + e];
            const int p = atomicAdd(&off[d], 1);
            p_lds[tid] = p;
            rec2[p] = make_int2(s, d);
        }
    }
    __syncthreads();
    const int row = tid >> 1;
    const int c0  = (tid & 1) * 64;
    const int e   = e0 + row;
    if (e < E) {
        const int p = p_lds[row];
        const f32x4* g = reinterpret_cast<const f32x4*>(ea + (size_t)e * D + c0);
        u16* dst = ea_s + (size_t)p * D + c0;
        f32x4 v[16];
        #pragma unroll
        for (int j = 0; j < 16; ++j) v[j] = __builtin_nontemporal_load(g + j);
        #pragma unroll
        for (int j = 0; j < 8; ++j) {
            u32x4 w;
            w.x = pk2(v[2*j].x,   v[2*j].y);   w.y = pk2(v[2*j].z,   v[2*j].w);
            w.z = pk2(v[2*j+1].x, v[2*j+1].y); w.w = pk2(v[2*j+1].z, v[2*j+1].w);
            __builtin_nontemporal_store(w, reinterpret_cast<u32x4*>(dst + 8*j));
        }
    }
}

// ======== sorted edge kernel v2: A from pre-permuted bf16 (sequential!) ========
// phases: We->LDS | A seq loads + MFMA | barrier | x[src] gather->LDS | epilogue | reduce
__global__ __launch_bounds__(256, 4)
void gine_edge_sorted2(const float* __restrict__ x,
                       const u16* __restrict__ ea_s,
                       const float* __restrict__ We,
                       const float* __restrict__ be,
                       const int2* __restrict__ rec2,
                       float* __restrict__ aggr,
                       int E)
{
    __shared__ u16 buf[128][LDK];     // We (bf16) -> x (bf16) -> msg (bf16)
    __shared__ int src_lds[128];
    __shared__ int dst_lds[128];

    const int tid = threadIdx.x;
    const int e0  = blockIdx.x * 128;

    {   // stage We (bf16) + records
        const int row = tid >> 1;
        const int c0  = (tid & 1) * 64;
        const float4* gw = reinterpret_cast<const float4*>(We + (size_t)row * D + c0);
        #pragma unroll
        for (int j = 0; j < 8; ++j) {
            float4 w0 = gw[2*j], w1 = gw[2*j+1];
            cvt_store8(&buf[row][c0 + 8*j], w0, w1);
        }
        if (tid < 128) {
            const int p = e0 + tid;
            if (p < E) {
                int2 r2 = rec2[p];
                src_lds[tid] = r2.x; dst_lds[tid] = r2.y;
            } else {
                src_lds[tid] = 0; dst_lds[tid] = -1;
            }
        }
    }
    __syncthreads();

    const int wave = tid >> 6, lane = tid & 63;
    const int lhi = lane >> 4, llo = lane & 15;
    const int r0 = wave * 32;   // wave owns 32 sorted rows x 128 cols

    f32x4 acc[2][8];
    #pragma unroll
    for (int m = 0; m < 2; ++m)
        #pragma unroll
        for (int n = 0; n < 8; ++n) acc[m][n] = (f32x4){0.f, 0.f, 0.f, 0.f};

    // A operand: SEQUENTIAL bf16 reads from the block's contiguous 32KB slab
    int ra = e0 + r0 + llo;      if (ra >= E) ra = E - 1;
    int rb = e0 + r0 + 16 + llo; if (rb >= E) rb = E - 1;
    const u16* pa_ = ea_s + (size_t)ra * D;
    const u16* pb_ = ea_s + (size_t)rb * D;

    u32x4 araw[2][4];
    #pragma unroll
    for (int kk = 0; kk < 4; ++kk) {
        const int o = kk * 32 + lhi * 8;
        araw[0][kk] = __builtin_nontemporal_load(reinterpret_cast<const u32x4*>(pa_ + o));
        araw[1][kk] = __builtin_nontemporal_load(reinterpret_cast<const u32x4*>(pb_ + o));
    }

    #pragma unroll
    for (int kk = 0; kk < 4; ++kk) {
        const int k0 = kk * 32 + lhi * 8;
        bf16x8 a0 = __builtin_bit_cast(bf16x8, araw[0][kk]);
        bf16x8 a1 = __builtin_bit_cast(bf16x8, araw[1][kk]);
        #pragma unroll
        for (int nf = 0; nf < 8; ++nf) {
            bf16x8 b = *reinterpret_cast<const bf16x8*>(&buf[nf*16 + llo][k0]);
            acc[0][nf] = __builtin_amdgcn_mfma_f32_16x16x32_bf16(a0, b, acc[0][nf], 0, 0, 0);
            acc[1][nf] = __builtin_amdgcn_mfma_f32_16x16x32_bf16(a1, b, acc[1][nf], 0, 0, 0);
        }
    }

    float bev[8];
    #pragma unroll
    for (int nf = 0; nf < 8; ++nf) bev[nf] = be[nf*16 + llo];

    __syncthreads();   // all waves done reading We

    {   // cooperative x[src] gather -> buf (bf16), deep-issue batches
        const int row = tid >> 1;
        const int c0  = (tid & 1) * 64;
        const int s   = src_lds[row];
        const f32x4* gx = reinterpret_cast<const f32x4*>(x + (size_t)s * D + c0);
        f32x4 xa[8];
        #pragma unroll
        for (int j = 0; j < 8; ++j) xa[j] = gx[j];
        #pragma unroll
        for (int j = 0; j < 4; ++j)
            cvt_store8v(&buf[row][c0 + 8*j], xa[2*j], xa[2*j+1]);
        #pragma unroll
        for (int j = 0; j < 8; ++j) xa[j] = gx[8 + j];
        #pragma unroll
        for (int j = 0; j < 4; ++j)
            cvt_store8v(&buf[row][c0 + 32 + 8*j], xa[2*j], xa[2*j+1]);
    }
    __syncthreads();

    // in-place epilogue: buf[row][col] = relu(acc + x + be)
    #pragma unroll
    for (int mf = 0; mf < 2; ++mf) {
        #pragma unroll
        for (int r = 0; r < 4; ++r) {
            const int row = r0 + mf*16 + lhi*4 + r;
            const bool valid = (e0 + row) < E;
            #pragma unroll
            for (int nf = 0; nf < 8; ++nf) {
                const int col = nf*16 + llo;
                const float v = acc[mf][nf][r] + bf2f(buf[row][col]) + bev[nf];
                buf[row][col] = valid ? f2bf(fmaxf(v, 0.0f)) : (u16)0;
            }
        }
    }
    __syncthreads();

    // segmented reduce, both 64-row halves in parallel (all 256 threads).
    {
        const int c   = tid & 127;
        const int h   = tid >> 7;
        const int rlo = h * 64;
        float sum = 0.0f;
        int prev  = dst_lds[rlo];
        int start = rlo;
        #pragma unroll 4
        for (int r = rlo; r < rlo + 64; ++r) {
            const float v = bf2f(buf[r][c]);
            const int d = dst_lds[r];
            if (d != prev) {
                if (prev >= 0) {
                    float* p = &aggr[(size_t)prev * D + c];
                    if (start == rlo) atomicAdd(p, sum);
                    else              *p = sum;     // complete run, exclusive
                }
                sum = 0.0f; prev = d; start = r;
            }
            sum += v;
        }
        if (prev >= 0) atomicAdd(&aggr[(size_t)prev * D + c], sum);
    }
}

// ======== mid-tier: round-7 sorted kernel (eid gather of f32 ea), ws-limited ========
__global__ __launch_bounds__(256)
void scatter_kernel(const int* __restrict__ ei, int* __restrict__ off,
                    int4* __restrict__ rec, int E) {
    int e = blockIdx.x * 256 + threadIdx.x;
    if (e < E) {
        int s = ei[e];
        int d = ei[E + e];
        int p = atomicAdd(&off[d], 1);
        rec[p] = make_int4(e, s, d, 0);
    }
}

__global__ __launch_bounds__(256, 4)
void gine_edge_sorted(const float* __restrict__ x,
                      const float* __restrict__ ea,
                      const float* __restrict__ We,
                      const float* __restrict__ be,
                      const int4* __restrict__ rec,
                      float* __restrict__ aggr,
                      int E)
{
    __shared__ u16 buf[128][LDK];
    __shared__ int eid_lds[128];
    __shared__ int src_lds[128];
    __shared__ int dst_lds[128];

    const int tid = threadIdx.x;
    const int e0  = blockIdx.x * 128;

    {
        const int row = tid >> 1;
        const int c0  = (tid & 1) * 64;
        const float4* gw = reinterpret_cast<const float4*>(We + (size_t)row * D + c0);
        #pragma unroll
        for (int j = 0; j < 8; ++j) {
            float4 w0 = gw[2*j], w1 = gw[2*j+1];
            cvt_store8(&buf[row][c0 + 8*j], w0, w1);
        }
        if (tid < 128) {
            const int p = e0 + tid;
            if (p < E) {
                int4 r4 = rec[p];
                eid_lds[tid] = r4.x; src_lds[tid] = r4.y; dst_lds[tid] = r4.z;
            } else {
                eid_lds[tid] = 0; src_lds[tid] = 0; dst_lds[tid] = -1;
            }
        }
    }
    __syncthreads();

    const int wave = tid >> 6, lane = tid & 63;
    const int lhi = lane >> 4, llo = lane & 15;
    const int r0 = wave * 32;

    f32x4 acc[2][8];
    #pragma unroll
    for (int m = 0; m < 2; ++m)
        #pragma unroll
        for (int n = 0; n < 8; ++n) acc[m][n] = (f32x4){0.f, 0.f, 0.f, 0.f};

    const f32x4* pa = reinterpret_cast<const f32x4*>(ea + (size_t)eid_lds[r0 + llo] * D);
    const f32x4* pb = reinterpret_cast<const f32x4*>(ea + (size_t)eid_lds[r0 + 16 + llo] * D);

    #pragma unroll
    for (int kk = 0; kk < 4; ++kk) {
        const int k0 = kk * 32 + lhi * 8;
        const int f4 = k0 >> 2;
        f32x4 u0 = __builtin_nontemporal_load(pa + f4);
        f32x4 u1 = __builtin_nontemporal_load(pa + f4 + 1);
        f32x4 v0 = __builtin_nontemporal_load(pb + f4);
        f32x4 v1 = __builtin_nontemporal_load(pb + f4 + 1);
        bf16x8 a0 = cvt8r(u0, u1);
        bf16x8 a1 = cvt8r(v0, v1);
        #pragma unroll
        for (int nf = 0; nf < 8; ++nf) {
            bf16x8 b = *reinterpret_cast<const bf16x8*>(&buf[nf*16 + llo][k0]);
            acc[0][nf] = __builtin_amdgcn_mfma_f32_16x16x32_bf16(a0, b, acc[0][nf], 0, 0, 0);
            acc[1][nf] = __builtin_amdgcn_mfma_f32_16x16x32_bf16(a1, b, acc[1][nf], 0, 0, 0);
        }
    }

    float bev[8];
    #pragma unroll
    for (int nf = 0; nf < 8; ++nf) bev[nf] = be[nf*16 + llo];

    __syncthreads();

    {
        const int row = tid >> 1;
        const int c0  = (tid & 1) * 64;
        const int s   = src_lds[row];
        const f32x4* gx = reinterpret_cast<const f32x4*>(x + (size_t)s * D + c0);
        f32x4 xa[8];
        #pragma unroll
        for (int j = 0; j < 8; ++j) xa[j] = gx[j];
        #pragma unroll
        for (int j = 0; j < 4; ++j)
            cvt_store8v(&buf[row][c0 + 8*j], xa[2*j], xa[2*j+1]);
        #pragma unroll
        for (int j = 0; j < 8; ++j) xa[j] = gx[8 + j];
        #pragma unroll
        for (int j = 0; j < 4; ++j)
            cvt_store8v(&buf[row][c0 + 32 + 8*j], xa[2*j], xa[2*j+1]);
    }
    __syncthreads();

    #pragma unroll
    for (int mf = 0; mf < 2; ++mf) {
        #pragma unroll
        for (int r = 0; r < 4; ++r) {
            const int row = r0 + mf*16 + lhi*4 + r;
            const bool valid = (e0 + row) < E;
            #pragma unroll
            for (int nf = 0; nf < 8; ++nf) {
                const int col = nf*16 + llo;
                const float v = acc[mf][nf][r] + bf2f(buf[row][col]) + bev[nf];
                buf[row][col] = valid ? f2bf(fmaxf(v, 0.0f)) : (u16)0;
            }
        }
    }
    __syncthreads();

    {
        const int c   = tid & 127;
        const int h   = tid >> 7;
        const int rlo = h * 64;
        float sum = 0.0f;
        int prev  = dst_lds[rlo];
        int start = rlo;
        #pragma unroll 4
        for (int r = rlo; r < rlo + 64; ++r) {
            const float v = bf2f(buf[r][c]);
            const int d = dst_lds[r];
            if (d != prev) {
                if (prev >= 0) {
                    float* p = &aggr[(size_t)prev * D + c];
                    if (start == rlo) atomicAdd(p, sum);
                    else              *p = sum;
                }
                sum = 0.0f; prev = d; start = r;
            }
            sum += v;
        }
        if (prev >= 0) atomicAdd(&aggr[(size_t)prev * D + c], sum);
    }
}

// ======== last-resort unsorted edge kernel ========
__global__ __launch_bounds__(256, 4)
void gine_edge(const float* __restrict__ x,
               const int* __restrict__ ei,
               const float* __restrict__ ea,
               const float* __restrict__ We,
               const float* __restrict__ be,
               float* __restrict__ aggr,
               int E)
{
    __shared__ u16 w_lds[128][LDK];
    __shared__ int sd_lds[2][128];

    const int tid = threadIdx.x;
    const int e0  = blockIdx.x * 128;

    {
        const int row = tid >> 1;
        const int c0  = (tid & 1) * 64;
        const float4* gw = reinterpret_cast<const float4*>(We + (size_t)row * D + c0);
        #pragma unroll
        for (int j = 0; j < 8; ++j) {
            float4 w0 = gw[2*j], w1 = gw[2*j+1];
            cvt_store8(&w_lds[row][c0 + 8*j], w0, w1);
        }
        const int r = tid & 127, which = tid >> 7;
        int erow = e0 + r;
        sd_lds[which][r] = (erow < E) ? ei[(size_t)which * E + erow] : 0;
    }
    __syncthreads();

    const int wave = tid >> 6, lane = tid & 63;
    const int lhi = lane >> 4, llo = lane & 15;
    const int r0 = wave * 32;

    f32x4 acc[2][8];
    #pragma unroll
    for (int m = 0; m < 2; ++m)
        #pragma unroll
        for (int n = 0; n < 8; ++n) acc[m][n] = (f32x4){0.f, 0.f, 0.f, 0.f};

    int ra = e0 + r0 + llo;      if (ra >= E) ra = E - 1;
    int rb = e0 + r0 + 16 + llo; if (rb >= E) rb = E - 1;
    const f32x4* pa = reinterpret_cast<const f32x4*>(ea + (size_t)ra * D);
    const f32x4* pb = reinterpret_cast<const f32x4*>(ea + (size_t)rb * D);

    #pragma unroll
    for (int kk = 0; kk < 4; ++kk) {
        const int k0 = kk * 32 + lhi * 8;
        const int f4 = k0 >> 2;
        f32x4 u0 = __builtin_nontemporal_load(pa + f4);
        f32x4 u1 = __builtin_nontemporal_load(pa + f4 + 1);
        f32x4 v0 = __builtin_nontemporal_load(pb + f4);
        f32x4 v1 = __builtin_nontemporal_load(pb + f4 + 1);
        bf16x8 a0 = cvt8r(u0, u1);
        bf16x8 a1 = cvt8r(v0, v1);
        #pragma unroll
        for (int nf = 0; nf < 8; ++nf) {
            bf16x8 b = *reinterpret_cast<const bf16x8*>(&w_lds[nf*16 + llo][k0]);
            acc[0][nf] = __builtin_amdgcn_mfma_f32_16x16x32_bf16(a0, b, acc[0][nf], 0, 0, 0);
            acc[1][nf] = __builtin_amdgcn_mfma_f32_16x16x32_bf16(a1, b, acc[1][nf], 0, 0, 0);
        }
    }

    float bev[8];
    #pragma unroll
    for (int nf = 0; nf < 8; ++nf) bev[nf] = be[nf*16 + llo];

    #pragma unroll
    for (int mf = 0; mf < 2; ++mf) {
        #pragma unroll
        for (int r = 0; r < 4; ++r) {
            const int row = r0 + mf*16 + lhi*4 + r;
            if (e0 + row >= E) continue;
            const int s = sd_lds[0][row];
            const int d = sd_lds[1][row];
            const float* xr  = x    + (size_t)s * D;
            float*      arow = aggr + (size_t)d * D;
            #pragma unroll
            for (int nf = 0; nf < 8; ++nf) {
                const int col = nf*16 + llo;
                float v = acc[mf][nf][r] + xr[col] + bev[nf];
                atomicAdd(&arow[col], fmaxf(v, 0.0f));
            }
        }
    }
}

// ---------------- node kernel: h0=(1+eps)x+aggr; GEMM1+BN+ReLU; GEMM2+b2; LN; relu(+x)
__global__ __launch_bounds__(256, 2)
void gine_node(const float* __restrict__ x,
               const float* __restrict__ aggr,
               const float* __restrict__ epsp,
               const float* __restrict__ W1,
               const float* __restrict__ b1,
               const float* __restrict__ bn_g,
               const float* __restrict__ bn_b,
               const float* __restrict__ bn_rm,
               const float* __restrict__ bn_rv,
               const float* __restrict__ W2,
               const float* __restrict__ b2,
               const float* __restrict__ ln_g,
               const float* __restrict__ ln_b,
               float* __restrict__ out,
               int N)
{
    __shared__ u16 h_lds[128][LDK];
    __shared__ u16 w_lds[128][LDK];

    const int tid = threadIdx.x;
    const int n0  = blockIdx.x * 128;
    const float epf = 1.0f + epsp[0];

    {
        const int row = tid >> 1;
        const int c0  = (tid & 1) * 64;
        int nrow = n0 + row; if (nrow >= N) nrow = N - 1;
        const float4* gx = reinterpret_cast<const float4*>(x    + (size_t)nrow * D + c0);
        const float4* ga = reinterpret_cast<const float4*>(aggr + (size_t)nrow * D + c0);
        const float4* gw = reinterpret_cast<const float4*>(W1   + (size_t)row  * D + c0);
        #pragma unroll
        for (int j = 0; j < 8; ++j) {
            float4 xv0 = gx[2*j], xv1 = gx[2*j+1];
            float4 av0 = ga[2*j], av1 = ga[2*j+1];
            float4 h0, h1;
            h0.x = epf*xv0.x + av0.x; h0.y = epf*xv0.y + av0.y;
            h0.z = epf*xv0.z + av0.z; h0.w = epf*xv0.w + av0.w;
            h1.x = epf*xv1.x + av1.x; h1.y = epf*xv1.y + av1.y;
            h1.z = epf*xv1.z + av1.z; h1.w = epf*xv1.w + av1.w;
            cvt_store8(&h_lds[row][c0 + 8*j], h0, h1);
            float4 w0 = gw[2*j], w1 = gw[2*j+1];
            cvt_store8(&w_lds[row][c0 + 8*j], w0, w1);
        }
    }
    __syncthreads();

    const int wave = tid >> 6, lane = tid & 63;
    const int lhi = lane >> 4, llo = lane & 15;
    const int r0 = wave * 32;

    f32x4 acc[2][8];
    #pragma unroll
    for (int m = 0; m < 2; ++m)
        #pragma unroll
        for (int n = 0; n < 8; ++n) acc[m][n] = (f32x4){0.f, 0.f, 0.f, 0.f};

    #pragma unroll
    for (int kk = 0; kk < 4; ++kk) {
        const int k0 = kk * 32 + lhi * 8;
        bf16x8 a0 = *reinterpret_cast<const bf16x8*>(&h_lds[r0 + llo][k0]);
        bf16x8 a1 = *reinterpret_cast<const bf16x8*>(&h_lds[r0 + 16 + llo][k0]);
        #pragma unroll
        for (int nf = 0; nf < 8; ++nf) {
            bf16x8 b = *reinterpret_cast<const bf16x8*>(&w_lds[nf*16 + llo][k0]);
            acc[0][nf] = __builtin_amdgcn_mfma_f32_16x16x32_bf16(a0, b, acc[0][nf], 0, 0, 0);
            acc[1][nf] = __builtin_amdgcn_mfma_f32_16x16x32_bf16(a1, b, acc[1][nf], 0, 0, 0);
        }
    }

    float sc[8], bi[8], b2v[8], lgv[8], lbv[8];
    #pragma unroll
    for (int nf = 0; nf < 8; ++nf) {
        const int c = nf*16 + llo;
        const float s = bn_g[c] * rsqrtf(bn_rv[c] + 1e-5f);
        sc[nf]  = s;
        bi[nf]  = (b1[c] - bn_rm[c]) * s + bn_b[c];
        b2v[nf] = b2[c];
        lgv[nf] = ln_g[c];
        lbv[nf] = ln_b[c];
    }

    __syncthreads();

    #pragma unroll
    for (int mf = 0; mf < 2; ++mf) {
        #pragma unroll
        for (int r = 0; r < 4; ++r) {
            const int row = r0 + mf*16 + lhi*4 + r;
            #pragma unroll
            for (int nf = 0; nf < 8; ++nf) {
                const int col = nf*16 + llo;
                const float v = fmaxf(acc[mf][nf][r] * sc[nf] + bi[nf], 0.0f);
                h_lds[row][col] = f2bf(v);
            }
        }
    }
    {
        const int row = tid >> 1;
        const int c0  = (tid & 1) * 64;
        const float4* gw = reinterpret_cast<const float4*>(W2 + (size_t)row * D + c0);
        #pragma unroll
        for (int j = 0; j < 8; ++j) {
            float4 w0 = gw[2*j], w1 = gw[2*j+1];
            cvt_store8(&w_lds[row][c0 + 8*j], w0, w1);
        }
    }
    __syncthreads();

    f32x4 acc2[2][8];
    #pragma unroll
    for (int m = 0; m < 2; ++m)
        #pragma unroll
        for (int n = 0; n < 8; ++n) acc2[m][n] = (f32x4){0.f, 0.f, 0.f, 0.f};

    #pragma unroll
    for (int kk = 0; kk < 4; ++kk) {
        const int k0 = kk * 32 + lhi * 8;
        bf16x8 a0 = *reinterpret_cast<const bf16x8*>(&h_lds[r0 + llo][k0]);
        bf16x8 a1 = *reinterpret_cast<const bf16x8*>(&h_lds[r0 + 16 + llo][k0]);
        #pragma unroll
        for (int nf = 0; nf < 8; ++nf) {
            bf16x8 b = *reinterpret_cast<const bf16x8*>(&w_lds[nf*16 + llo][k0]);
            acc2[0][nf] = __builtin_amdgcn_mfma_f32_16x16x32_bf16(a0, b, acc2[0][nf], 0, 0, 0);
            acc2[1][nf] = __builtin_amdgcn_mfma_f32_16x16x32_bf16(a1, b, acc2[1][nf], 0, 0, 0);
        }
    }

    #pragma unroll
    for (int mf = 0; mf < 2; ++mf) {
        #pragma unroll
        for (int r = 0; r < 4; ++r) {
            float hv[8];
            float ssum = 0.f;
            #pragma unroll
            for (int nf = 0; nf < 8; ++nf) {
                const float v = acc2[mf][nf][r] + b2v[nf];
                hv[nf] = v; ssum += v;
            }
            ssum += __shfl_xor(ssum, 1); ssum += __shfl_xor(ssum, 2);
            ssum += __shfl_xor(ssum, 4); ssum += __shfl_xor(ssum, 8);
            const float mu = ssum * (1.0f/128.0f);
            float qs = 0.f;
            #pragma unroll
            for (int nf = 0; nf < 8; ++nf) { const float dd = hv[nf] - mu; qs += dd*dd; }
            qs += __shfl_xor(qs, 1); qs += __shfl_xor(qs, 2);
            qs += __shfl_xor(qs, 4); qs += __shfl_xor(qs, 8);
            const float rstd = rsqrtf(qs * (1.0f/128.0f) + 1e-5f);

            const int nrow = n0 + r0 + mf*16 + lhi*4 + r;
            if (nrow < N) {
                const float* xr   = x   + (size_t)nrow * D;
                float*       orow = out + (size_t)nrow * D;
                #pragma unroll
                for (int nf = 0; nf < 8; ++nf) {
                    const int col = nf*16 + llo;
                    const float v = (hv[nf] - mu) * rstd * lgv[nf] + lbv[nf] + xr[col];
                    orow[col] = fmaxf(v, 0.0f);
                }
            }
        }
    }
}

extern "C" void kernel_launch(void* const* d_in, const int* in_sizes, int n_in,
                              void* d_out, int out_size, void* d_ws, size_t ws_size,
                              hipStream_t stream) {
    const float* x     = (const float*)d_in[0];
    const int*   ei    = (const int*)d_in[1];
    const float* ea    = (const float*)d_in[2];
    const float* epsp  = (const float*)d_in[3];
    const float* We    = (const float*)d_in[4];
    const float* be    = (const float*)d_in[5];
    const float* W1    = (const float*)d_in[6];
    const float* b1    = (const float*)d_in[7];
    const float* bn_g  = (const float*)d_in[8];
    const float* bn_b  = (const float*)d_in[9];
    const float* bn_rm = (const float*)d_in[10];
    const float* bn_rv = (const float*)d_in[11];
    const float* W2    = (const float*)d_in[12];
    const float* b2    = (const float*)d_in[13];
    const float* ln_g  = (const float*)d_in[14];
    const float* ln_b  = (const float*)d_in[15];
    float* out = (float*)d_out;

    const int N = in_sizes[0] / D;     // 50000
    const int E = in_sizes[2] / D;     // 800000

    const size_t aggr_bytes = (size_t)N * D * sizeof(float);        // 25.6 MB
    const size_t cnt_elems  = ((size_t)N + 1023) & ~(size_t)1023;
    const size_t cnt_bytes  = cnt_elems * sizeof(int);
    const size_t bsum_bytes = 1024;
    const size_t rec2_bytes = (size_t)E * sizeof(int2);             // 6.4 MB
    const size_t eas_bytes  = (size_t)E * D * sizeof(u16);          // 204.8 MB
    const size_t rec4_bytes = (size_t)E * sizeof(int4);             // 12.8 MB
    const size_t base       = aggr_bytes + 2 * cnt_bytes + bsum_bytes;
    const size_t need_full  = base + rec2_bytes + eas_bytes;        // ~237 MB
    const size_t need_mid   = base + rec4_bytes;                    // ~39 MB
    const int nsb = (int)(cnt_elems / 1024);

    char* wsb = (char*)d_ws;
    const int tblocks = (E + 255) / 256;
    const int eblocks = (E + 127) / 128;
    const int nblocks = (N + 127) / 128;

    if (ws_size >= need_full && nsb <= 256) {
        float* aggr    = (float*)(wsb);
        int*   counts  = (int*)(wsb + aggr_bytes);
        int*   offsets = (int*)(wsb + aggr_bytes + cnt_bytes);
        int*   bsum    = (int*)(wsb + aggr_bytes + 2*cnt_bytes);
        int2*  rec2    = (int2*)(wsb + base);
        u16*   ea_s    = (u16*)(wsb + base + rec2_bytes);

        (void)hipMemsetAsync(aggr, 0, aggr_bytes, stream);
        (void)hipMemsetAsync(counts, 0, cnt_bytes, stream);

        hist_kernel<<<tblocks, 256, 0, stream>>>(ei, counts, E);
        scan_partial<<<nsb, 256, 0, stream>>>(counts, bsum);
        scan_bsum<<<1, 256, 0, stream>>>(bsum, nsb);
        scan_emit<<<nsb, 256, 0, stream>>>(counts, bsum, offsets);
        scatter_permute<<<eblocks, 256, 0, stream>>>(ei, offsets, ea, rec2, ea_s, E);

        gine_edge_sorted2<<<eblocks, 256, 0, stream>>>(x, ea_s, We, be, rec2, aggr, E);
        gine_node<<<nblocks, 256, 0, stream>>>(x, aggr, epsp, W1, b1, bn_g, bn_b,
                                               bn_rm, bn_rv, W2, b2, ln_g, ln_b, out, N);
    } else if (ws_size >= need_mid && nsb <= 256) {
        float* aggr    = (float*)(wsb);
        int*   counts  = (int*)(wsb + aggr_bytes);
        int*   offsets = (int*)(wsb + aggr_bytes + cnt_bytes);
        int*   bsum    = (int*)(wsb + aggr_bytes + 2*cnt_bytes);
        int4*  rec     = (int4*)(wsb + base);

        (void)hipMemsetAsync(aggr, 0, aggr_bytes, stream);
        (void)hipMemsetAsync(counts, 0, cnt_bytes, stream);

        hist_kernel<<<tblocks, 256, 0, stream>>>(ei, counts, E);
        scan_partial<<<nsb, 256, 0, stream>>>(counts, bsum);
        scan_bsum<<<1, 256, 0, stream>>>(bsum, nsb);
        scan_emit<<<nsb, 256, 0, stream>>>(counts, bsum, offsets);
        scatter_kernel<<<tblocks, 256, 0, stream>>>(ei, offsets, rec, E);

        gine_edge_sorted<<<eblocks, 256, 0, stream>>>(x, ea, We, be, rec, aggr, E);
        gine_node<<<nblocks, 256, 0, stream>>>(x, aggr, epsp, W1, b1, bn_g, bn_b,
                                               bn_rm, bn_rv, W2, b2, ln_g, ln_b, out, N);
    } else {
        float* aggr = (ws_size >= aggr_bytes) ? (float*)d_ws : out;
        (void)hipMemsetAsync(aggr, 0, aggr_bytes, stream);
        gine_edge<<<eblocks, 256, 0, stream>>>(x, ei, ea, We, be, aggr, E);
        gine_node<<<nblocks, 256, 0, stream>>>(x, aggr, epsp, W1, b1, bn_g, bn_b,
                                               bn_rm, bn_rv, W2, b2, ln_g, ln_b, out, N);
    }
}

// Round 9
// 546.835 us; speedup vs baseline: 2.1696x; 2.1696x over previous
//
#include <hip/hip_runtime.h>
#include <hip/hip_bf16.h>

#define D 128
#define LDK 136  // padded LDS row: 136 bf16 = 272B

typedef __bf16 bf16x8 __attribute__((ext_vector_type(8)));
typedef float  f32x4  __attribute__((ext_vector_type(4)));
typedef unsigned int u32x4 __attribute__((ext_vector_type(4)));
typedef unsigned short u16;

__device__ __forceinline__ u16 f2bf(float f) {
    unsigned int u = __builtin_bit_cast(unsigned int, f);
    u = u + 0x7FFFu + ((u >> 16) & 1u);
    return (u16)(u >> 16);
}
__device__ __forceinline__ float bf2f(u16 h) {
    unsigned int u = ((unsigned int)h) << 16;
    return __builtin_bit_cast(float, u);
}
__device__ __forceinline__ unsigned int pk2(float lo, float hi) {
    return (unsigned int)f2bf(lo) | ((unsigned int)f2bf(hi) << 16);
}
__device__ __forceinline__ void cvt_store8(u16* dst, float4 a, float4 b) {
    uint4 v;
    v.x = pk2(a.x, a.y); v.y = pk2(a.z, a.w);
    v.z = pk2(b.x, b.y); v.w = pk2(b.z, b.w);
    *reinterpret_cast<uint4*>(dst) = v;
}
__device__ __forceinline__ void cvt_store8v(u16* dst, f32x4 a, f32x4 b) {
    uint4 v;
    v.x = pk2(a.x, a.y); v.y = pk2(a.z, a.w);
    v.z = pk2(b.x, b.y); v.w = pk2(b.z, b.w);
    *reinterpret_cast<uint4*>(dst) = v;
}
__device__ __forceinline__ bf16x8 cvt8r(f32x4 a, f32x4 b) {
    u32x4 v;
    v.x = pk2(a.x, a.y); v.y = pk2(a.z, a.w);
    v.z = pk2(b.x, b.y); v.w = pk2(b.z, b.w);
    return __builtin_bit_cast(bf16x8, v);
}

// ======== sort machinery: counting sort of edges by dst ========
__global__ __launch_bounds__(256)
void hist_kernel(const int* __restrict__ ei, int* __restrict__ counts, int E) {
    int e = blockIdx.x * 256 + threadIdx.x;
    if (e < E) atomicAdd(&counts[ei[E + e]], 1);
}

__global__ __launch_bounds__(256)
void scan_partial(const int* __restrict__ counts, int* __restrict__ bsum) {
    const int b = blockIdx.x, t = threadIdx.x;
    const int4 v = reinterpret_cast<const int4*>(counts + (size_t)b * 1024)[t];
    int s = v.x + v.y + v.z + v.w;
    #pragma unroll
    for (int off = 1; off < 64; off <<= 1) s += __shfl_xor(s, off);
    __shared__ int ws[4];
    if ((t & 63) == 0) ws[t >> 6] = s;
    __syncthreads();
    if (t == 0) bsum[b] = ws[0] + ws[1] + ws[2] + ws[3];
}
__global__ __launch_bounds__(256)
void scan_bsum(int* __restrict__ bsum, int nb) {
    const int t = threadIdx.x;
    int s = (t < nb) ? bsum[t] : 0;
    int inc = s;
    const int lane = t & 63;
    #pragma unroll
    for (int off = 1; off < 64; off <<= 1) {
        int v = __shfl_up(inc, off);
        if (lane >= off) inc += v;
    }
    __shared__ int ws[4];
    if (lane == 63) ws[t >> 6] = inc;
    __syncthreads();
    int woff = 0;
    for (int i = 0; i < (t >> 6); ++i) woff += ws[i];
    if (t < nb) bsum[t] = woff + inc - s;
}
__global__ __launch_bounds__(256)
void scan_emit(const int* __restrict__ counts, const int* __restrict__ bsum,
               int* __restrict__ offsets) {
    const int b = blockIdx.x, t = threadIdx.x;
    const int4 v = reinterpret_cast<const int4*>(counts + (size_t)b * 1024)[t];
    const int s = v.x + v.y + v.z + v.w;
    int inc = s;
    const int lane = t & 63;
    #pragma unroll
    for (int off = 1; off < 64; off <<= 1) {
        int u = __shfl_up(inc, off);
        if (lane >= off) inc += u;
    }
    __shared__ int ws[4];
    if (lane == 63) ws[t >> 6] = inc;
    __syncthreads();
    int woff = bsum[b];
    for (int i = 0; i < (t >> 6); ++i) woff += ws[i];
    int e0 = woff + inc - s;
    int4 o;
    o.x = e0; o.y = e0 + v.x; o.z = o.y + v.y; o.w = o.z + v.z;
    reinterpret_cast<int4*>(offsets + (size_t)b * 1024)[t] = o;
}

// ======== scatter+permute v2: full-line random writes ========
// 16 lanes per row x 16B each -> one wave store instruction = 4 rows x 256B
// contiguous (all full 64B lines). REGULAR stores so L2 merges/writes clean
// lines (evidence: aggr interior stores show no write amplification).
__global__ __launch_bounds__(256)
void scatter_permute(const int* __restrict__ ei, int* __restrict__ off,
                     const float* __restrict__ ea,
                     int2* __restrict__ rec2, u16* __restrict__ ea_s, int E) {
    __shared__ int p_lds[128];
    const int tid = threadIdx.x;
    const int e0  = blockIdx.x * 128;
    if (tid < 128) {
        const int e = e0 + tid;
        if (e < E) {
            const int s = ei[e];
            const int d = ei[E + e];
            const int p = atomicAdd(&off[d], 1);
            p_lds[tid] = p;
            rec2[p] = make_int2(s, d);
        }
    }
    __syncthreads();
    const int lane16 = tid & 15;     // 16B chunk within the bf16 row
    const int rbase  = tid >> 4;     // 0..15
    // issue all loads first (deep), then convert+store
    f32x4 fa[8], fb[8];
    #pragma unroll
    for (int i = 0; i < 8; ++i) {
        const int e = e0 + rbase + 16*i;
        if (e < E) {
            const f32x4* g = reinterpret_cast<const f32x4*>(ea + (size_t)e * D + lane16*8);
            fa[i] = __builtin_nontemporal_load(g);
            fb[i] = __builtin_nontemporal_load(g + 1);
        }
    }
    #pragma unroll
    for (int i = 0; i < 8; ++i) {
        const int row = rbase + 16*i;
        const int e = e0 + row;
        if (e < E) {
            const int p = p_lds[row];
            u32x4 w;
            w.x = pk2(fa[i].x, fa[i].y); w.y = pk2(fa[i].z, fa[i].w);
            w.z = pk2(fb[i].x, fb[i].y); w.w = pk2(fb[i].z, fb[i].w);
            *reinterpret_cast<u32x4*>(ea_s + (size_t)p * D + lane16*8) = w;
        }
    }
}

// ======== sorted edge kernel v3: sequential bf16 A + T14 x-load hoist ========
__global__ __launch_bounds__(256, 4)
void gine_edge_sorted3(const float* __restrict__ x,
                       const u16* __restrict__ ea_s,
                       const float* __restrict__ We,
                       const float* __restrict__ be,
                       const int2* __restrict__ rec2,
                       float* __restrict__ aggr,
                       int E)
{
    __shared__ u16 buf[128][LDK];     // We (bf16) -> x (bf16) -> msg (bf16)
    __shared__ int src_lds[128];
    __shared__ int dst_lds[128];

    const int tid = threadIdx.x;
    const int e0  = blockIdx.x * 128;

    {   // stage We (bf16) + records
        const int row = tid >> 1;
        const int c0  = (tid & 1) * 64;
        const float4* gw = reinterpret_cast<const float4*>(We + (size_t)row * D + c0);
        #pragma unroll
        for (int j = 0; j < 8; ++j) {
            float4 w0 = gw[2*j], w1 = gw[2*j+1];
            cvt_store8(&buf[row][c0 + 8*j], w0, w1);
        }
        if (tid < 128) {
            const int p = e0 + tid;
            if (p < E) {
                int2 r2 = rec2[p];
                src_lds[tid] = r2.x; dst_lds[tid] = r2.y;
            } else {
                src_lds[tid] = 0; dst_lds[tid] = -1;
            }
        }
    }
    __syncthreads();

    const int wave = tid >> 6, lane = tid & 63;
    const int lhi = lane >> 4, llo = lane & 15;
    const int r0 = wave * 32;

    // issue A loads first (MFMA waits on these) — sequential bf16 slab
    int ra = e0 + r0 + llo;      if (ra >= E) ra = E - 1;
    int rb = e0 + r0 + 16 + llo; if (rb >= E) rb = E - 1;
    const u16* pa_ = ea_s + (size_t)ra * D;
    const u16* pb_ = ea_s + (size_t)rb * D;
    u32x4 araw[2][4];
    #pragma unroll
    for (int kk = 0; kk < 4; ++kk) {
        const int o = kk * 32 + lhi * 8;
        araw[0][kk] = __builtin_nontemporal_load(reinterpret_cast<const u32x4*>(pa_ + o));
        araw[1][kk] = __builtin_nontemporal_load(reinterpret_cast<const u32x4*>(pb_ + o));
    }

    // T14: issue first half of x[src] row (8 x 16B) BEFORE MFMA — hides under it
    const int xrow = tid >> 1;
    const int xc0  = (tid & 1) * 64;
    const f32x4* gx = reinterpret_cast<const f32x4*>(x + (size_t)src_lds[xrow] * D + xc0);
    f32x4 xa[8];
    #pragma unroll
    for (int j = 0; j < 8; ++j) xa[j] = gx[j];

    f32x4 acc[2][8];
    #pragma unroll
    for (int m = 0; m < 2; ++m)
        #pragma unroll
        for (int n = 0; n < 8; ++n) acc[m][n] = (f32x4){0.f, 0.f, 0.f, 0.f};

    #pragma unroll
    for (int kk = 0; kk < 4; ++kk) {
        const int k0 = kk * 32 + lhi * 8;
        bf16x8 a0 = __builtin_bit_cast(bf16x8, araw[0][kk]);
        bf16x8 a1 = __builtin_bit_cast(bf16x8, araw[1][kk]);
        #pragma unroll
        for (int nf = 0; nf < 8; ++nf) {
            bf16x8 b = *reinterpret_cast<const bf16x8*>(&buf[nf*16 + llo][k0]);
            acc[0][nf] = __builtin_amdgcn_mfma_f32_16x16x32_bf16(a0, b, acc[0][nf], 0, 0, 0);
            acc[1][nf] = __builtin_amdgcn_mfma_f32_16x16x32_bf16(a1, b, acc[1][nf], 0, 0, 0);
        }
    }

    // issue second half of x row (araw regs now dead)
    f32x4 xb[8];
    #pragma unroll
    for (int j = 0; j < 8; ++j) xb[j] = gx[8 + j];

    float bev[8];
    #pragma unroll
    for (int nf = 0; nf < 8; ++nf) bev[nf] = be[nf*16 + llo];

    __syncthreads();   // all waves done reading We

    // store x to LDS (bf16)
    #pragma unroll
    for (int j = 0; j < 4; ++j)
        cvt_store8v(&buf[xrow][xc0 + 8*j], xa[2*j], xa[2*j+1]);
    #pragma unroll
    for (int j = 0; j < 4; ++j)
        cvt_store8v(&buf[xrow][xc0 + 32 + 8*j], xb[2*j], xb[2*j+1]);
    __syncthreads();

    // in-place epilogue: buf[row][col] = relu(acc + x + be)
    #pragma unroll
    for (int mf = 0; mf < 2; ++mf) {
        #pragma unroll
        for (int r = 0; r < 4; ++r) {
            const int row = r0 + mf*16 + lhi*4 + r;
            const bool valid = (e0 + row) < E;
            #pragma unroll
            for (int nf = 0; nf < 8; ++nf) {
                const int col = nf*16 + llo;
                const float v = acc[mf][nf][r] + bf2f(buf[row][col]) + bev[nf];
                buf[row][col] = valid ? f2bf(fmaxf(v, 0.0f)) : (u16)0;
            }
        }
    }
    __syncthreads();

    // segmented reduce, both 64-row halves in parallel (256 threads)
    {
        const int c   = tid & 127;
        const int h   = tid >> 7;
        const int rlo = h * 64;
        float sum = 0.0f;
        int prev  = dst_lds[rlo];
        int start = rlo;
        #pragma unroll 4
        for (int r = rlo; r < rlo + 64; ++r) {
            const float v = bf2f(buf[r][c]);
            const int d = dst_lds[r];
            if (d != prev) {
                if (prev >= 0) {
                    float* p = &aggr[(size_t)prev * D + c];
                    if (start == rlo) atomicAdd(p, sum);
                    else              *p = sum;     // complete run, exclusive
                }
                sum = 0.0f; prev = d; start = r;
            }
            sum += v;
        }
        if (prev >= 0) atomicAdd(&aggr[(size_t)prev * D + c], sum);
    }
}

// ======== mid-tier: round-7 sorted kernel (eid gather of f32 ea) ========
__global__ __launch_bounds__(256)
void scatter_kernel(const int* __restrict__ ei, int* __restrict__ off,
                    int4* __restrict__ rec, int E) {
    int e = blockIdx.x * 256 + threadIdx.x;
    if (e < E) {
        int s = ei[e];
        int d = ei[E + e];
        int p = atomicAdd(&off[d], 1);
        rec[p] = make_int4(e, s, d, 0);
    }
}

__global__ __launch_bounds__(256, 4)
void gine_edge_sorted(const float* __restrict__ x,
                      const float* __restrict__ ea,
                      const float* __restrict__ We,
                      const float* __restrict__ be,
                      const int4* __restrict__ rec,
                      float* __restrict__ aggr,
                      int E)
{
    __shared__ u16 buf[128][LDK];
    __shared__ int eid_lds[128];
    __shared__ int src_lds[128];
    __shared__ int dst_lds[128];

    const int tid = threadIdx.x;
    const int e0  = blockIdx.x * 128;

    {
        const int row = tid >> 1;
        const int c0  = (tid & 1) * 64;
        const float4* gw = reinterpret_cast<const float4*>(We + (size_t)row * D + c0);
        #pragma unroll
        for (int j = 0; j < 8; ++j) {
            float4 w0 = gw[2*j], w1 = gw[2*j+1];
            cvt_store8(&buf[row][c0 + 8*j], w0, w1);
        }
        if (tid < 128) {
            const int p = e0 + tid;
            if (p < E) {
                int4 r4 = rec[p];
                eid_lds[tid] = r4.x; src_lds[tid] = r4.y; dst_lds[tid] = r4.z;
            } else {
                eid_lds[tid] = 0; src_lds[tid] = 0; dst_lds[tid] = -1;
            }
        }
    }
    __syncthreads();

    const int wave = tid >> 6, lane = tid & 63;
    const int lhi = lane >> 4, llo = lane & 15;
    const int r0 = wave * 32;

    f32x4 acc[2][8];
    #pragma unroll
    for (int m = 0; m < 2; ++m)
        #pragma unroll
        for (int n = 0; n < 8; ++n) acc[m][n] = (f32x4){0.f, 0.f, 0.f, 0.f};

    const f32x4* pa = reinterpret_cast<const f32x4*>(ea + (size_t)eid_lds[r0 + llo] * D);
    const f32x4* pb = reinterpret_cast<const f32x4*>(ea + (size_t)eid_lds[r0 + 16 + llo] * D);

    #pragma unroll
    for (int kk = 0; kk < 4; ++kk) {
        const int k0 = kk * 32 + lhi * 8;
        const int f4 = k0 >> 2;
        f32x4 u0 = __builtin_nontemporal_load(pa + f4);
        f32x4 u1 = __builtin_nontemporal_load(pa + f4 + 1);
        f32x4 v0 = __builtin_nontemporal_load(pb + f4);
        f32x4 v1 = __builtin_nontemporal_load(pb + f4 + 1);
        bf16x8 a0 = cvt8r(u0, u1);
        bf16x8 a1 = cvt8r(v0, v1);
        #pragma unroll
        for (int nf = 0; nf < 8; ++nf) {
            bf16x8 b = *reinterpret_cast<const bf16x8*>(&buf[nf*16 + llo][k0]);
            acc[0][nf] = __builtin_amdgcn_mfma_f32_16x16x32_bf16(a0, b, acc[0][nf], 0, 0, 0);
            acc[1][nf] = __builtin_amdgcn_mfma_f32_16x16x32_bf16(a1, b, acc[1][nf], 0, 0, 0);
        }
    }

    float bev[8];
    #pragma unroll
    for (int nf = 0; nf < 8; ++nf) bev[nf] = be[nf*16 + llo];

    __syncthreads();

    {
        const int row = tid >> 1;
        const int c0  = (tid & 1) * 64;
        const int s   = src_lds[row];
        const f32x4* gx = reinterpret_cast<const f32x4*>(x + (size_t)s * D + c0);
        f32x4 xa[8];
        #pragma unroll
        for (int j = 0; j < 8; ++j) xa[j] = gx[j];
        #pragma unroll
        for (int j = 0; j < 4; ++j)
            cvt_store8v(&buf[row][c0 + 8*j], xa[2*j], xa[2*j+1]);
        #pragma unroll
        for (int j = 0; j < 8; ++j) xa[j] = gx[8 + j];
        #pragma unroll
        for (int j = 0; j < 4; ++j)
            cvt_store8v(&buf[row][c0 + 32 + 8*j], xa[2*j], xa[2*j+1]);
    }
    __syncthreads();

    #pragma unroll
    for (int mf = 0; mf < 2; ++mf) {
        #pragma unroll
        for (int r = 0; r < 4; ++r) {
            const int row = r0 + mf*16 + lhi*4 + r;
            const bool valid = (e0 + row) < E;
            #pragma unroll
            for (int nf = 0; nf < 8; ++nf) {
                const int col = nf*16 + llo;
                const float v = acc[mf][nf][r] + bf2f(buf[row][col]) + bev[nf];
                buf[row][col] = valid ? f2bf(fmaxf(v, 0.0f)) : (u16)0;
            }
        }
    }
    __syncthreads();

    {
        const int c   = tid & 127;
        const int h   = tid >> 7;
        const int rlo = h * 64;
        float sum = 0.0f;
        int prev  = dst_lds[rlo];
        int start = rlo;
        #pragma unroll 4
        for (int r = rlo; r < rlo + 64; ++r) {
            const float v = bf2f(buf[r][c]);
            const int d = dst_lds[r];
            if (d != prev) {
                if (prev >= 0) {
                    float* p = &aggr[(size_t)prev * D + c];
                    if (start == rlo) atomicAdd(p, sum);
                    else              *p = sum;
                }
                sum = 0.0f; prev = d; start = r;
            }
            sum += v;
        }
        if (prev >= 0) atomicAdd(&aggr[(size_t)prev * D + c], sum);
    }
}

// ======== last-resort unsorted edge kernel ========
__global__ __launch_bounds__(256, 4)
void gine_edge(const float* __restrict__ x,
               const int* __restrict__ ei,
               const float* __restrict__ ea,
               const float* __restrict__ We,
               const float* __restrict__ be,
               float* __restrict__ aggr,
               int E)
{
    __shared__ u16 w_lds[128][LDK];
    __shared__ int sd_lds[2][128];

    const int tid = threadIdx.x;
    const int e0  = blockIdx.x * 128;

    {
        const int row = tid >> 1;
        const int c0  = (tid & 1) * 64;
        const float4* gw = reinterpret_cast<const float4*>(We + (size_t)row * D + c0);
        #pragma unroll
        for (int j = 0; j < 8; ++j) {
            float4 w0 = gw[2*j], w1 = gw[2*j+1];
            cvt_store8(&w_lds[row][c0 + 8*j], w0, w1);
        }
        const int r = tid & 127, which = tid >> 7;
        int erow = e0 + r;
        sd_lds[which][r] = (erow < E) ? ei[(size_t)which * E + erow] : 0;
    }
    __syncthreads();

    const int wave = tid >> 6, lane = tid & 63;
    const int lhi = lane >> 4, llo = lane & 15;
    const int r0 = wave * 32;

    f32x4 acc[2][8];
    #pragma unroll
    for (int m = 0; m < 2; ++m)
        #pragma unroll
        for (int n = 0; n < 8; ++n) acc[m][n] = (f32x4){0.f, 0.f, 0.f, 0.f};

    int ra = e0 + r0 + llo;      if (ra >= E) ra = E - 1;
    int rb = e0 + r0 + 16 + llo; if (rb >= E) rb = E - 1;
    const f32x4* pa = reinterpret_cast<const f32x4*>(ea + (size_t)ra * D);
    const f32x4* pb = reinterpret_cast<const f32x4*>(ea + (size_t)rb * D);

    #pragma unroll
    for (int kk = 0; kk < 4; ++kk) {
        const int k0 = kk * 32 + lhi * 8;
        const int f4 = k0 >> 2;
        f32x4 u0 = __builtin_nontemporal_load(pa + f4);
        f32x4 u1 = __builtin_nontemporal_load(pa + f4 + 1);
        f32x4 v0 = __builtin_nontemporal_load(pb + f4);
        f32x4 v1 = __builtin_nontemporal_load(pb + f4 + 1);
        bf16x8 a0 = cvt8r(u0, u1);
        bf16x8 a1 = cvt8r(v0, v1);
        #pragma unroll
        for (int nf = 0; nf < 8; ++nf) {
            bf16x8 b = *reinterpret_cast<const bf16x8*>(&w_lds[nf*16 + llo][k0]);
            acc[0][nf] = __builtin_amdgcn_mfma_f32_16x16x32_bf16(a0, b, acc[0][nf], 0, 0, 0);
            acc[1][nf] = __builtin_amdgcn_mfma_f32_16x16x32_bf16(a1, b, acc[1][nf], 0, 0, 0);
        }
    }

    float bev[8];
    #pragma unroll
    for (int nf = 0; nf < 8; ++nf) bev[nf] = be[nf*16 + llo];

    #pragma unroll
    for (int mf = 0; mf < 2; ++mf) {
        #pragma unroll
        for (int r = 0; r < 4; ++r) {
            const int row = r0 + mf*16 + lhi*4 + r;
            if (e0 + row >= E) continue;
            const int s = sd_lds[0][row];
            const int d = sd_lds[1][row];
            const float* xr  = x    + (size_t)s * D;
            float*      arow = aggr + (size_t)d * D;
            #pragma unroll
            for (int nf = 0; nf < 8; ++nf) {
                const int col = nf*16 + llo;
                float v = acc[mf][nf][r] + xr[col] + bev[nf];
                atomicAdd(&arow[col], fmaxf(v, 0.0f));
            }
        }
    }
}

// ---------------- node kernel ----------------
__global__ __launch_bounds__(256, 2)
void gine_node(const float* __restrict__ x,
               const float* __restrict__ aggr,
               const float* __restrict__ epsp,
               const float* __restrict__ W1,
               const float* __restrict__ b1,
               const float* __restrict__ bn_g,
               const float* __restrict__ bn_b,
               const float* __restrict__ bn_rm,
               const float* __restrict__ bn_rv,
               const float* __restrict__ W2,
               const float* __restrict__ b2,
               const float* __restrict__ ln_g,
               const float* __restrict__ ln_b,
               float* __restrict__ out,
               int N)
{
    __shared__ u16 h_lds[128][LDK];
    __shared__ u16 w_lds[128][LDK];

    const int tid = threadIdx.x;
    const int n0  = blockIdx.x * 128;
    const float epf = 1.0f + epsp[0];

    {
        const int row = tid >> 1;
        const int c0  = (tid & 1) * 64;
        int nrow = n0 + row; if (nrow >= N) nrow = N - 1;
        const float4* gx = reinterpret_cast<const float4*>(x    + (size_t)nrow * D + c0);
        const float4* ga = reinterpret_cast<const float4*>(aggr + (size_t)nrow * D + c0);
        const float4* gw = reinterpret_cast<const float4*>(W1   + (size_t)row  * D + c0);
        #pragma unroll
        for (int j = 0; j < 8; ++j) {
            float4 xv0 = gx[2*j], xv1 = gx[2*j+1];
            float4 av0 = ga[2*j], av1 = ga[2*j+1];
            float4 h0, h1;
            h0.x = epf*xv0.x + av0.x; h0.y = epf*xv0.y + av0.y;
            h0.z = epf*xv0.z + av0.z; h0.w = epf*xv0.w + av0.w;
            h1.x = epf*xv1.x + av1.x; h1.y = epf*xv1.y + av1.y;
            h1.z = epf*xv1.z + av1.z; h1.w = epf*xv1.w + av1.w;
            cvt_store8(&h_lds[row][c0 + 8*j], h0, h1);
            float4 w0 = gw[2*j], w1 = gw[2*j+1];
            cvt_store8(&w_lds[row][c0 + 8*j], w0, w1);
        }
    }
    __syncthreads();

    const int wave = tid >> 6, lane = tid & 63;
    const int lhi = lane >> 4, llo = lane & 15;
    const int r0 = wave * 32;

    f32x4 acc[2][8];
    #pragma unroll
    for (int m = 0; m < 2; ++m)
        #pragma unroll
        for (int n = 0; n < 8; ++n) acc[m][n] = (f32x4){0.f, 0.f, 0.f, 0.f};

    #pragma unroll
    for (int kk = 0; kk < 4; ++kk) {
        const int k0 = kk * 32 + lhi * 8;
        bf16x8 a0 = *reinterpret_cast<const bf16x8*>(&h_lds[r0 + llo][k0]);
        bf16x8 a1 = *reinterpret_cast<const bf16x8*>(&h_lds[r0 + 16 + llo][k0]);
        #pragma unroll
        for (int nf = 0; nf < 8; ++nf) {
            bf16x8 b = *reinterpret_cast<const bf16x8*>(&w_lds[nf*16 + llo][k0]);
            acc[0][nf] = __builtin_amdgcn_mfma_f32_16x16x32_bf16(a0, b, acc[0][nf], 0, 0, 0);
            acc[1][nf] = __builtin_amdgcn_mfma_f32_16x16x32_bf16(a1, b, acc[1][nf], 0, 0, 0);
        }
    }

    float sc[8], bi[8], b2v[8], lgv[8], lbv[8];
    #pragma unroll
    for (int nf = 0; nf < 8; ++nf) {
        const int c = nf*16 + llo;
        const float s = bn_g[c] * rsqrtf(bn_rv[c] + 1e-5f);
        sc[nf]  = s;
        bi[nf]  = (b1[c] - bn_rm[c]) * s + bn_b[c];
        b2v[nf] = b2[c];
        lgv[nf] = ln_g[c];
        lbv[nf] = ln_b[c];
    }

    __syncthreads();

    #pragma unroll
    for (int mf = 0; mf < 2; ++mf) {
        #pragma unroll
        for (int r = 0; r < 4; ++r) {
            const int row = r0 + mf*16 + lhi*4 + r;
            #pragma unroll
            for (int nf = 0; nf < 8; ++nf) {
                const int col = nf*16 + llo;
                const float v = fmaxf(acc[mf][nf][r] * sc[nf] + bi[nf], 0.0f);
                h_lds[row][col] = f2bf(v);
            }
        }
    }
    {
        const int row = tid >> 1;
        const int c0  = (tid & 1) * 64;
        const float4* gw = reinterpret_cast<const float4*>(W2 + (size_t)row * D + c0);
        #pragma unroll
        for (int j = 0; j < 8; ++j) {
            float4 w0 = gw[2*j], w1 = gw[2*j+1];
            cvt_store8(&w_lds[row][c0 + 8*j], w0, w1);
        }
    }
    __syncthreads();

    f32x4 acc2[2][8];
    #pragma unroll
    for (int m = 0; m < 2; ++m)
        #pragma unroll
        for (int n = 0; n < 8; ++n) acc2[m][n] = (f32x4){0.f, 0.f, 0.f, 0.f};

    #pragma unroll
    for (int kk = 0; kk < 4; ++kk) {
        const int k0 = kk * 32 + lhi * 8;
        bf16x8 a0 = *reinterpret_cast<const bf16x8*>(&h_lds[r0 + llo][k0]);
        bf16x8 a1 = *reinterpret_cast<const bf16x8*>(&h_lds[r0 + 16 + llo][k0]);
        #pragma unroll
        for (int nf = 0; nf < 8; ++nf) {
            bf16x8 b = *reinterpret_cast<const bf16x8*>(&w_lds[nf*16 + llo][k0]);
            acc2[0][nf] = __builtin_amdgcn_mfma_f32_16x16x32_bf16(a0, b, acc2[0][nf], 0, 0, 0);
            acc2[1][nf] = __builtin_amdgcn_mfma_f32_16x16x32_bf16(a1, b, acc2[1][nf], 0, 0, 0);
        }
    }

    #pragma unroll
    for (int mf = 0; mf < 2; ++mf) {
        #pragma unroll
        for (int r = 0; r < 4; ++r) {
            float hv[8];
            float ssum = 0.f;
            #pragma unroll
            for (int nf = 0; nf < 8; ++nf) {
                const float v = acc2[mf][nf][r] + b2v[nf];
                hv[nf] = v; ssum += v;
            }
            ssum += __shfl_xor(ssum, 1); ssum += __shfl_xor(ssum, 2);
            ssum += __shfl_xor(ssum, 4); ssum += __shfl_xor(ssum, 8);
            const float mu = ssum * (1.0f/128.0f);
            float qs = 0.f;
            #pragma unroll
            for (int nf = 0; nf < 8; ++nf) { const float dd = hv[nf] - mu; qs += dd*dd; }
            qs += __shfl_xor(qs, 1); qs += __shfl_xor(qs, 2);
            qs += __shfl_xor(qs, 4); qs += __shfl_xor(qs, 8);
            const float rstd = rsqrtf(qs * (1.0f/128.0f) + 1e-5f);

            const int nrow = n0 + r0 + mf*16 + lhi*4 + r;
            if (nrow < N) {
                const float* xr   = x   + (size_t)nrow * D;
                float*       orow = out + (size_t)nrow * D;
                #pragma unroll
                for (int nf = 0; nf < 8; ++nf) {
                    const int col = nf*16 + llo;
                    const float v = (hv[nf] - mu) * rstd * lgv[nf] + lbv[nf] + xr[col];
                    orow[col] = fmaxf(v, 0.0f);
                }
            }
        }
    }
}

extern "C" void kernel_launch(void* const* d_in, const int* in_sizes, int n_in,
                              void* d_out, int out_size, void* d_ws, size_t ws_size,
                              hipStream_t stream) {
    const float* x     = (const float*)d_in[0];
    const int*   ei    = (const int*)d_in[1];
    const float* ea    = (const float*)d_in[2];
    const float* epsp  = (const float*)d_in[3];
    const float* We    = (const float*)d_in[4];
    const float* be    = (const float*)d_in[5];
    const float* W1    = (const float*)d_in[6];
    const float* b1    = (const float*)d_in[7];
    const float* bn_g  = (const float*)d_in[8];
    const float* bn_b  = (const float*)d_in[9];
    const float* bn_rm = (const float*)d_in[10];
    const float* bn_rv = (const float*)d_in[11];
    const float* W2    = (const float*)d_in[12];
    const float* b2    = (const float*)d_in[13];
    const float* ln_g  = (const float*)d_in[14];
    const float* ln_b  = (const float*)d_in[15];
    float* out = (float*)d_out;

    const int N = in_sizes[0] / D;     // 50000
    const int E = in_sizes[2] / D;     // 800000

    const size_t aggr_bytes = (size_t)N * D * sizeof(float);        // 25.6 MB
    const size_t cnt_elems  = ((size_t)N + 1023) & ~(size_t)1023;
    const size_t cnt_bytes  = cnt_elems * sizeof(int);
    const size_t bsum_bytes = 1024;
    const size_t rec2_bytes = (size_t)E * sizeof(int2);             // 6.4 MB
    const size_t eas_bytes  = (size_t)E * D * sizeof(u16);          // 204.8 MB
    const size_t rec4_bytes = (size_t)E * sizeof(int4);             // 12.8 MB
    const size_t base       = aggr_bytes + 2 * cnt_bytes + bsum_bytes;
    const size_t need_full  = base + rec2_bytes + eas_bytes;        // ~237 MB
    const size_t need_mid   = base + rec4_bytes;                    // ~39 MB
    const int nsb = (int)(cnt_elems / 1024);

    char* wsb = (char*)d_ws;
    const int tblocks = (E + 255) / 256;
    const int eblocks = (E + 127) / 128;
    const int nblocks = (N + 127) / 128;

    if (ws_size >= need_full && nsb <= 256) {
        float* aggr    = (float*)(wsb);
        int*   counts  = (int*)(wsb + aggr_bytes);
        int*   offsets = (int*)(wsb + aggr_bytes + cnt_bytes);
        int*   bsum    = (int*)(wsb + aggr_bytes + 2*cnt_bytes);
        int2*  rec2    = (int2*)(wsb + base);
        u16*   ea_s    = (u16*)(wsb + base + rec2_bytes);

        (void)hipMemsetAsync(aggr, 0, aggr_bytes, stream);
        (void)hipMemsetAsync(counts, 0, cnt_bytes, stream);

        hist_kernel<<<tblocks, 256, 0, stream>>>(ei, counts, E);
        scan_partial<<<nsb, 256, 0, stream>>>(counts, bsum);
        scan_bsum<<<1, 256, 0, stream>>>(bsum, nsb);
        scan_emit<<<nsb, 256, 0, stream>>>(counts, bsum, offsets);
        scatter_permute<<<eblocks, 256, 0, stream>>>(ei, offsets, ea, rec2, ea_s, E);

        gine_edge_sorted3<<<eblocks, 256, 0, stream>>>(x, ea_s, We, be, rec2, aggr, E);
        gine_node<<<nblocks, 256, 0, stream>>>(x, aggr, epsp, W1, b1, bn_g, bn_b,
                                               bn_rm, bn_rv, W2, b2, ln_g, ln_b, out, N);
    } else if (ws_size >= need_mid && nsb <= 256) {
        float* aggr    = (float*)(wsb);
        int*   counts  = (int*)(wsb + aggr_bytes);
        int*   offsets = (int*)(wsb + aggr_bytes + cnt_bytes);
        int*   bsum    = (int*)(wsb + aggr_bytes + 2*cnt_bytes);
        int4*  rec     = (int4*)(wsb + base);

        (void)hipMemsetAsync(aggr, 0, aggr_bytes, stream);
        (void)hipMemsetAsync(counts, 0, cnt_bytes, stream);

        hist_kernel<<<tblocks, 256, 0, stream>>>(ei, counts, E);
        scan_partial<<<nsb, 256, 0, stream>>>(counts, bsum);
        scan_bsum<<<1, 256, 0, stream>>>(bsum, nsb);
        scan_emit<<<nsb, 256, 0, stream>>>(counts, bsum, offsets);
        scatter_kernel<<<tblocks, 256, 0, stream>>>(ei, offsets, rec, E);

        gine_edge_sorted<<<eblocks, 256, 0, stream>>>(x, ea, We, be, rec, aggr, E);
        gine_node<<<nblocks, 256, 0, stream>>>(x, aggr, epsp, W1, b1, bn_g, bn_b,
                                               bn_rm, bn_rv, W2, b2, ln_g, ln_b, out, N);
    } else {
        float* aggr = (ws_size >= aggr_bytes) ? (float*)d_ws : out;
        (void)hipMemsetAsync(aggr, 0, aggr_bytes, stream);
        gine_edge<<<eblocks, 256, 0, stream>>>(x, ei, ea, We, be, aggr, E);
        gine_node<<<nblocks, 256, 0, stream>>>(x, aggr, epsp, W1, b1, bn_g, bn_b,
                                               bn_rm, bn_rv, W2, b2, ln_g, ln_b, out, N);
    }
}

// Round 10
// 439.016 us; speedup vs baseline: 2.7024x; 1.2456x over previous
//
#include <hip/hip_runtime.h>
#include <hip/hip_bf16.h>

#define D 128
#define LDK 136  // padded LDS row: 136 bf16 = 272B

typedef __bf16 bf16x8 __attribute__((ext_vector_type(8)));
typedef float  f32x4  __attribute__((ext_vector_type(4)));
typedef unsigned int u32x4 __attribute__((ext_vector_type(4)));
typedef unsigned short u16;

__device__ __forceinline__ u16 f2bf(float f) {
    unsigned int u = __builtin_bit_cast(unsigned int, f);
    u = u + 0x7FFFu + ((u >> 16) & 1u);
    return (u16)(u >> 16);
}
__device__ __forceinline__ float bf2f(u16 h) {
    unsigned int u = ((unsigned int)h) << 16;
    return __builtin_bit_cast(float, u);
}
__device__ __forceinline__ unsigned int pk2(float lo, float hi) {
    return (unsigned int)f2bf(lo) | ((unsigned int)f2bf(hi) << 16);
}
__device__ __forceinline__ void cvt_store8(u16* dst, float4 a, float4 b) {
    uint4 v;
    v.x = pk2(a.x, a.y); v.y = pk2(a.z, a.w);
    v.z = pk2(b.x, b.y); v.w = pk2(b.z, b.w);
    *reinterpret_cast<uint4*>(dst) = v;
}
__device__ __forceinline__ void cvt_store8v(u16* dst, f32x4 a, f32x4 b) {
    uint4 v;
    v.x = pk2(a.x, a.y); v.y = pk2(a.z, a.w);
    v.z = pk2(b.x, b.y); v.w = pk2(b.z, b.w);
    *reinterpret_cast<uint4*>(dst) = v;
}
__device__ __forceinline__ bf16x8 cvt8r(f32x4 a, f32x4 b) {
    u32x4 v;
    v.x = pk2(a.x, a.y); v.y = pk2(a.z, a.w);
    v.z = pk2(b.x, b.y); v.w = pk2(b.z, b.w);
    return __builtin_bit_cast(bf16x8, v);
}

// ======== sort machinery: counting sort of edges by dst ========
__global__ __launch_bounds__(256)
void hist_kernel(const int* __restrict__ ei, int* __restrict__ counts, int E) {
    int e = blockIdx.x * 256 + threadIdx.x;
    if (e < E) atomicAdd(&counts[ei[E + e]], 1);
}

__global__ __launch_bounds__(256)
void scan_partial(const int* __restrict__ counts, int* __restrict__ bsum) {
    const int b = blockIdx.x, t = threadIdx.x;
    const int4 v = reinterpret_cast<const int4*>(counts + (size_t)b * 1024)[t];
    int s = v.x + v.y + v.z + v.w;
    #pragma unroll
    for (int off = 1; off < 64; off <<= 1) s += __shfl_xor(s, off);
    __shared__ int ws[4];
    if ((t & 63) == 0) ws[t >> 6] = s;
    __syncthreads();
    if (t == 0) bsum[b] = ws[0] + ws[1] + ws[2] + ws[3];
}
__global__ __launch_bounds__(256)
void scan_bsum(int* __restrict__ bsum, int nb) {
    const int t = threadIdx.x;
    int s = (t < nb) ? bsum[t] : 0;
    int inc = s;
    const int lane = t & 63;
    #pragma unroll
    for (int off = 1; off < 64; off <<= 1) {
        int v = __shfl_up(inc, off);
        if (lane >= off) inc += v;
    }
    __shared__ int ws[4];
    if (lane == 63) ws[t >> 6] = inc;
    __syncthreads();
    int woff = 0;
    for (int i = 0; i < (t >> 6); ++i) woff += ws[i];
    if (t < nb) bsum[t] = woff + inc - s;
}
__global__ __launch_bounds__(256)
void scan_emit(const int* __restrict__ counts, const int* __restrict__ bsum,
               int* __restrict__ offsets) {
    const int b = blockIdx.x, t = threadIdx.x;
    const int4 v = reinterpret_cast<const int4*>(counts + (size_t)b * 1024)[t];
    const int s = v.x + v.y + v.z + v.w;
    int inc = s;
    const int lane = t & 63;
    #pragma unroll
    for (int off = 1; off < 64; off <<= 1) {
        int u = __shfl_up(inc, off);
        if (lane >= off) inc += u;
    }
    __shared__ int ws[4];
    if (lane == 63) ws[t >> 6] = inc;
    __syncthreads();
    int woff = bsum[b];
    for (int i = 0; i < (t >> 6); ++i) woff += ws[i];
    int e0 = woff + inc - s;
    int4 o;
    o.x = e0; o.y = e0 + v.x; o.z = o.y + v.y; o.w = o.z + v.z;
    reinterpret_cast<int4*>(offsets + (size_t)b * 1024)[t] = o;
}

// scatter: one packed 16B record per edge at its sorted position
__global__ __launch_bounds__(256)
void scatter_kernel(const int* __restrict__ ei, int* __restrict__ off,
                    int4* __restrict__ rec, int E) {
    int e = blockIdx.x * 256 + threadIdx.x;
    if (e < E) {
        int s = ei[e];
        int d = ei[E + e];
        int p = atomicAdd(&off[d], 1);
        rec[p] = make_int4(e, s, d, 0);
    }
}

// ======== sorted edge kernel, 512 threads (8 waves, 16-row M-tiles) ========
// Same 128-edge tile & LDS as r7 but 2x the waves/CU (32 = HW max at 4 blocks):
// halves per-wave phase latency, doubles latency-hiding TLP, reduce serial 64->32.
__global__ __launch_bounds__(512, 8)
void gine_edge_sorted(const float* __restrict__ x,
                      const float* __restrict__ ea,
                      const float* __restrict__ We,
                      const float* __restrict__ be,
                      const int4* __restrict__ rec,
                      float* __restrict__ aggr,
                      int E)
{
    __shared__ u16 buf[128][LDK];     // We (bf16) -> x (bf16) -> msg (bf16)
    __shared__ int eid_lds[128];
    __shared__ int src_lds[128];
    __shared__ int dst_lds[128];

    const int tid = threadIdx.x;      // 0..511
    const int e0  = blockIdx.x * 128;

    {   // stage We: thread t -> row t>>2, 32-col chunk (t&3)*32
        const int row = tid >> 2;
        const int c0  = (tid & 3) * 32;
        const float4* gw = reinterpret_cast<const float4*>(We + (size_t)row * D + c0);
        #pragma unroll
        for (int j = 0; j < 4; ++j) {
            float4 w0 = gw[2*j], w1 = gw[2*j+1];
            cvt_store8(&buf[row][c0 + 8*j], w0, w1);
        }
        if (tid < 128) {
            const int p = e0 + tid;
            if (p < E) {
                int4 r4 = rec[p];
                eid_lds[tid] = r4.x; src_lds[tid] = r4.y; dst_lds[tid] = r4.z;
            } else {
                eid_lds[tid] = 0; src_lds[tid] = 0; dst_lds[tid] = -1;
            }
        }
    }
    __syncthreads();

    const int wave = tid >> 6, lane = tid & 63;
    const int lhi = lane >> 4, llo = lane & 15;
    const int r0 = wave * 16;         // wave owns 16 sorted rows x 128 cols

    f32x4 acc[8];
    #pragma unroll
    for (int n = 0; n < 8; ++n) acc[n] = (f32x4){0.f, 0.f, 0.f, 0.f};

    const f32x4* pa = reinterpret_cast<const f32x4*>(ea + (size_t)eid_lds[r0 + llo] * D);

    // 2-deep K-step pipeline (2 x 16B loads per step)
#define LOADG(G, KK) { const int f4_ = ((KK)*32 + lhi*8) >> 2;                 \
        G[0] = __builtin_nontemporal_load(pa + f4_);                           \
        G[1] = __builtin_nontemporal_load(pa + f4_ + 1); }
#define MFMAG(G, KK) { bf16x8 a_ = cvt8r(G[0], G[1]);                          \
        const int k0_ = (KK)*32 + lhi*8;                                       \
        _Pragma("unroll")                                                      \
        for (int nf = 0; nf < 8; ++nf) {                                       \
            bf16x8 b_ = *reinterpret_cast<const bf16x8*>(&buf[nf*16 + llo][k0_]); \
            acc[nf] = __builtin_amdgcn_mfma_f32_16x16x32_bf16(a_, b_, acc[nf], 0, 0, 0); \
        } }

    f32x4 gA[2], gB[2];
    LOADG(gA, 0); LOADG(gB, 1);
    MFMAG(gA, 0); LOADG(gA, 2);
    MFMAG(gB, 1); LOADG(gB, 3);
    MFMAG(gA, 2); MFMAG(gB, 3);
#undef LOADG
#undef MFMAG

    float bev[8];
    #pragma unroll
    for (int nf = 0; nf < 8; ++nf) bev[nf] = be[nf*16 + llo];

    __syncthreads();   // all waves done reading We

    {   // cooperative x[src] gather -> buf (bf16): thread t -> row t>>2, 32 cols
        const int row = tid >> 2;
        const int c0  = (tid & 3) * 32;
        const f32x4* gx = reinterpret_cast<const f32x4*>(x + (size_t)src_lds[row] * D + c0);
        f32x4 xa[4];
        #pragma unroll
        for (int j = 0; j < 4; ++j) xa[j] = gx[j];
        cvt_store8v(&buf[row][c0 +  0], xa[0], xa[1]);
        cvt_store8v(&buf[row][c0 +  8], xa[2], xa[3]);
        #pragma unroll
        for (int j = 0; j < 4; ++j) xa[j] = gx[4 + j];
        cvt_store8v(&buf[row][c0 + 16], xa[0], xa[1]);
        cvt_store8v(&buf[row][c0 + 24], xa[2], xa[3]);
    }
    __syncthreads();

    // in-place epilogue: buf[row][col] = relu(acc + x + be)
    #pragma unroll
    for (int r = 0; r < 4; ++r) {
        const int row = r0 + lhi*4 + r;
        const bool valid = (e0 + row) < E;
        #pragma unroll
        for (int nf = 0; nf < 8; ++nf) {
            const int col = nf*16 + llo;
            const float v = acc[nf][r] + bf2f(buf[row][col]) + bev[nf];
            buf[row][col] = valid ? f2bf(fmaxf(v, 0.0f)) : (u16)0;
        }
    }
    __syncthreads();

    // segmented reduce: 4 row-quarters in parallel (512 threads, 32 iters each).
    // Runs interior to a quarter -> exclusive plain store; boundary runs -> atomic.
    {
        const int c   = tid & 127;
        const int rlo = (tid >> 7) * 32;
        float sum = 0.0f;
        int prev  = dst_lds[rlo];
        int start = rlo;
        #pragma unroll 4
        for (int r = rlo; r < rlo + 32; ++r) {
            const float v = bf2f(buf[r][c]);
            const int d = dst_lds[r];
            if (d != prev) {
                if (prev >= 0) {
                    float* p = &aggr[(size_t)prev * D + c];
                    if (start == rlo) atomicAdd(p, sum);
                    else              *p = sum;     // complete run, exclusive
                }
                sum = 0.0f; prev = d; start = r;
            }
            sum += v;
        }
        if (prev >= 0) atomicAdd(&aggr[(size_t)prev * D + c], sum);
    }
}

// ======== last-resort unsorted edge kernel (ws too small) ========
__global__ __launch_bounds__(256, 4)
void gine_edge(const float* __restrict__ x,
               const int* __restrict__ ei,
               const float* __restrict__ ea,
               const float* __restrict__ We,
               const float* __restrict__ be,
               float* __restrict__ aggr,
               int E)
{
    __shared__ u16 w_lds[128][LDK];
    __shared__ int sd_lds[2][128];

    const int tid = threadIdx.x;
    const int e0  = blockIdx.x * 128;

    {
        const int row = tid >> 1;
        const int c0  = (tid & 1) * 64;
        const float4* gw = reinterpret_cast<const float4*>(We + (size_t)row * D + c0);
        #pragma unroll
        for (int j = 0; j < 8; ++j) {
            float4 w0 = gw[2*j], w1 = gw[2*j+1];
            cvt_store8(&w_lds[row][c0 + 8*j], w0, w1);
        }
        const int r = tid & 127, which = tid >> 7;
        int erow = e0 + r;
        sd_lds[which][r] = (erow < E) ? ei[(size_t)which * E + erow] : 0;
    }
    __syncthreads();

    const int wave = tid >> 6, lane = tid & 63;
    const int lhi = lane >> 4, llo = lane & 15;
    const int r0 = wave * 32;

    f32x4 acc[2][8];
    #pragma unroll
    for (int m = 0; m < 2; ++m)
        #pragma unroll
        for (int n = 0; n < 8; ++n) acc[m][n] = (f32x4){0.f, 0.f, 0.f, 0.f};

    int ra = e0 + r0 + llo;      if (ra >= E) ra = E - 1;
    int rb = e0 + r0 + 16 + llo; if (rb >= E) rb = E - 1;
    const f32x4* pa = reinterpret_cast<const f32x4*>(ea + (size_t)ra * D);
    const f32x4* pb = reinterpret_cast<const f32x4*>(ea + (size_t)rb * D);

    #pragma unroll
    for (int kk = 0; kk < 4; ++kk) {
        const int k0 = kk * 32 + lhi * 8;
        const int f4 = k0 >> 2;
        f32x4 u0 = __builtin_nontemporal_load(pa + f4);
        f32x4 u1 = __builtin_nontemporal_load(pa + f4 + 1);
        f32x4 v0 = __builtin_nontemporal_load(pb + f4);
        f32x4 v1 = __builtin_nontemporal_load(pb + f4 + 1);
        bf16x8 a0 = cvt8r(u0, u1);
        bf16x8 a1 = cvt8r(v0, v1);
        #pragma unroll
        for (int nf = 0; nf < 8; ++nf) {
            bf16x8 b = *reinterpret_cast<const bf16x8*>(&w_lds[nf*16 + llo][k0]);
            acc[0][nf] = __builtin_amdgcn_mfma_f32_16x16x32_bf16(a0, b, acc[0][nf], 0, 0, 0);
            acc[1][nf] = __builtin_amdgcn_mfma_f32_16x16x32_bf16(a1, b, acc[1][nf], 0, 0, 0);
        }
    }

    float bev[8];
    #pragma unroll
    for (int nf = 0; nf < 8; ++nf) bev[nf] = be[nf*16 + llo];

    #pragma unroll
    for (int mf = 0; mf < 2; ++mf) {
        #pragma unroll
        for (int r = 0; r < 4; ++r) {
            const int row = r0 + mf*16 + lhi*4 + r;
            if (e0 + row >= E) continue;
            const int s = sd_lds[0][row];
            const int d = sd_lds[1][row];
            const float* xr  = x    + (size_t)s * D;
            float*      arow = aggr + (size_t)d * D;
            #pragma unroll
            for (int nf = 0; nf < 8; ++nf) {
                const int col = nf*16 + llo;
                float v = acc[mf][nf][r] + xr[col] + bev[nf];
                atomicAdd(&arow[col], fmaxf(v, 0.0f));
            }
        }
    }
}

// ---------------- node kernel ----------------
__global__ __launch_bounds__(256, 2)
void gine_node(const float* __restrict__ x,
               const float* __restrict__ aggr,
               const float* __restrict__ epsp,
               const float* __restrict__ W1,
               const float* __restrict__ b1,
               const float* __restrict__ bn_g,
               const float* __restrict__ bn_b,
               const float* __restrict__ bn_rm,
               const float* __restrict__ bn_rv,
               const float* __restrict__ W2,
               const float* __restrict__ b2,
               const float* __restrict__ ln_g,
               const float* __restrict__ ln_b,
               float* __restrict__ out,
               int N)
{
    __shared__ u16 h_lds[128][LDK];
    __shared__ u16 w_lds[128][LDK];

    const int tid = threadIdx.x;
    const int n0  = blockIdx.x * 128;
    const float epf = 1.0f + epsp[0];

    {
        const int row = tid >> 1;
        const int c0  = (tid & 1) * 64;
        int nrow = n0 + row; if (nrow >= N) nrow = N - 1;
        const float4* gx = reinterpret_cast<const float4*>(x    + (size_t)nrow * D + c0);
        const float4* ga = reinterpret_cast<const float4*>(aggr + (size_t)nrow * D + c0);
        const float4* gw = reinterpret_cast<const float4*>(W1   + (size_t)row  * D + c0);
        #pragma unroll
        for (int j = 0; j < 8; ++j) {
            float4 xv0 = gx[2*j], xv1 = gx[2*j+1];
            float4 av0 = ga[2*j], av1 = ga[2*j+1];
            float4 h0, h1;
            h0.x = epf*xv0.x + av0.x; h0.y = epf*xv0.y + av0.y;
            h0.z = epf*xv0.z + av0.z; h0.w = epf*xv0.w + av0.w;
            h1.x = epf*xv1.x + av1.x; h1.y = epf*xv1.y + av1.y;
            h1.z = epf*xv1.z + av1.z; h1.w = epf*xv1.w + av1.w;
            cvt_store8(&h_lds[row][c0 + 8*j], h0, h1);
            float4 w0 = gw[2*j], w1 = gw[2*j+1];
            cvt_store8(&w_lds[row][c0 + 8*j], w0, w1);
        }
    }
    __syncthreads();

    const int wave = tid >> 6, lane = tid & 63;
    const int lhi = lane >> 4, llo = lane & 15;
    const int r0 = wave * 32;

    f32x4 acc[2][8];
    #pragma unroll
    for (int m = 0; m < 2; ++m)
        #pragma unroll
        for (int n = 0; n < 8; ++n) acc[m][n] = (f32x4){0.f, 0.f, 0.f, 0.f};

    #pragma unroll
    for (int kk = 0; kk < 4; ++kk) {
        const int k0 = kk * 32 + lhi * 8;
        bf16x8 a0 = *reinterpret_cast<const bf16x8*>(&h_lds[r0 + llo][k0]);
        bf16x8 a1 = *reinterpret_cast<const bf16x8*>(&h_lds[r0 + 16 + llo][k0]);
        #pragma unroll
        for (int nf = 0; nf < 8; ++nf) {
            bf16x8 b = *reinterpret_cast<const bf16x8*>(&w_lds[nf*16 + llo][k0]);
            acc[0][nf] = __builtin_amdgcn_mfma_f32_16x16x32_bf16(a0, b, acc[0][nf], 0, 0, 0);
            acc[1][nf] = __builtin_amdgcn_mfma_f32_16x16x32_bf16(a1, b, acc[1][nf], 0, 0, 0);
        }
    }

    float sc[8], bi[8], b2v[8], lgv[8], lbv[8];
    #pragma unroll
    for (int nf = 0; nf < 8; ++nf) {
        const int c = nf*16 + llo;
        const float s = bn_g[c] * rsqrtf(bn_rv[c] + 1e-5f);
        sc[nf]  = s;
        bi[nf]  = (b1[c] - bn_rm[c]) * s + bn_b[c];
        b2v[nf] = b2[c];
        lgv[nf] = ln_g[c];
        lbv[nf] = ln_b[c];
    }

    __syncthreads();

    #pragma unroll
    for (int mf = 0; mf < 2; ++mf) {
        #pragma unroll
        for (int r = 0; r < 4; ++r) {
            const int row = r0 + mf*16 + lhi*4 + r;
            #pragma unroll
            for (int nf = 0; nf < 8; ++nf) {
                const int col = nf*16 + llo;
                const float v = fmaxf(acc[mf][nf][r] * sc[nf] + bi[nf], 0.0f);
                h_lds[row][col] = f2bf(v);
            }
        }
    }
    {
        const int row = tid >> 1;
        const int c0  = (tid & 1) * 64;
        const float4* gw = reinterpret_cast<const float4*>(W2 + (size_t)row * D + c0);
        #pragma unroll
        for (int j = 0; j < 8; ++j) {
            float4 w0 = gw[2*j], w1 = gw[2*j+1];
            cvt_store8(&w_lds[row][c0 + 8*j], w0, w1);
        }
    }
    __syncthreads();

    f32x4 acc2[2][8];
    #pragma unroll
    for (int m = 0; m < 2; ++m)
        #pragma unroll
        for (int n = 0; n < 8; ++n) acc2[m][n] = (f32x4){0.f, 0.f, 0.f, 0.f};

    #pragma unroll
    for (int kk = 0; kk < 4; ++kk) {
        const int k0 = kk * 32 + lhi * 8;
        bf16x8 a0 = *reinterpret_cast<const bf16x8*>(&h_lds[r0 + llo][k0]);
        bf16x8 a1 = *reinterpret_cast<const bf16x8*>(&h_lds[r0 + 16 + llo][k0]);
        #pragma unroll
        for (int nf = 0; nf < 8; ++nf) {
            bf16x8 b = *reinterpret_cast<const bf16x8*>(&w_lds[nf*16 + llo][k0]);
            acc2[0][nf] = __builtin_amdgcn_mfma_f32_16x16x32_bf16(a0, b, acc2[0][nf], 0, 0, 0);
            acc2[1][nf] = __builtin_amdgcn_mfma_f32_16x16x32_bf16(a1, b, acc2[1][nf], 0, 0, 0);
        }
    }

    #pragma unroll
    for (int mf = 0; mf < 2; ++mf) {
        #pragma unroll
        for (int r = 0; r < 4; ++r) {
            float hv[8];
            float ssum = 0.f;
            #pragma unroll
            for (int nf = 0; nf < 8; ++nf) {
                const float v = acc2[mf][nf][r] + b2v[nf];
                hv[nf] = v; ssum += v;
            }
            ssum += __shfl_xor(ssum, 1); ssum += __shfl_xor(ssum, 2);
            ssum += __shfl_xor(ssum, 4); ssum += __shfl_xor(ssum, 8);
            const float mu = ssum * (1.0f/128.0f);
            float qs = 0.f;
            #pragma unroll
            for (int nf = 0; nf < 8; ++nf) { const float dd = hv[nf] - mu; qs += dd*dd; }
            qs += __shfl_xor(qs, 1); qs += __shfl_xor(qs, 2);
            qs += __shfl_xor(qs, 4); qs += __shfl_xor(qs, 8);
            const float rstd = rsqrtf(qs * (1.0f/128.0f) + 1e-5f);

            const int nrow = n0 + r0 + mf*16 + lhi*4 + r;
            if (nrow < N) {
                const float* xr   = x   + (size_t)nrow * D;
                float*       orow = out + (size_t)nrow * D;
                #pragma unroll
                for (int nf = 0; nf < 8; ++nf) {
                    const int col = nf*16 + llo;
                    const float v = (hv[nf] - mu) * rstd * lgv[nf] + lbv[nf] + xr[col];
                    orow[col] = fmaxf(v, 0.0f);
                }
            }
        }
    }
}

extern "C" void kernel_launch(void* const* d_in, const int* in_sizes, int n_in,
                              void* d_out, int out_size, void* d_ws, size_t ws_size,
                              hipStream_t stream) {
    const float* x     = (const float*)d_in[0];
    const int*   ei    = (const int*)d_in[1];
    const float* ea    = (const float*)d_in[2];
    const float* epsp  = (const float*)d_in[3];
    const float* We    = (const float*)d_in[4];
    const float* be    = (const float*)d_in[5];
    const float* W1    = (const float*)d_in[6];
    const float* b1    = (const float*)d_in[7];
    const float* bn_g  = (const float*)d_in[8];
    const float* bn_b  = (const float*)d_in[9];
    const float* bn_rm = (const float*)d_in[10];
    const float* bn_rv = (const float*)d_in[11];
    const float* W2    = (const float*)d_in[12];
    const float* b2    = (const float*)d_in[13];
    const float* ln_g  = (const float*)d_in[14];
    const float* ln_b  = (const float*)d_in[15];
    float* out = (float*)d_out;

    const int N = in_sizes[0] / D;     // 50000
    const int E = in_sizes[2] / D;     // 800000

    const size_t aggr_bytes = (size_t)N * D * sizeof(float);        // 25.6 MB
    const size_t cnt_elems  = ((size_t)N + 1023) & ~(size_t)1023;
    const size_t cnt_bytes  = cnt_elems * sizeof(int);
    const size_t bsum_bytes = 1024;
    const size_t rec4_bytes = (size_t)E * sizeof(int4);             // 12.8 MB
    const size_t base       = aggr_bytes + 2 * cnt_bytes + bsum_bytes;
    const size_t need_mid   = base + rec4_bytes;                    // ~39 MB
    const int nsb = (int)(cnt_elems / 1024);

    char* wsb = (char*)d_ws;
    const int tblocks = (E + 255) / 256;
    const int eblocks = (E + 127) / 128;
    const int nblocks = (N + 127) / 128;

    if (ws_size >= need_mid && nsb <= 256) {
        float* aggr    = (float*)(wsb);
        int*   counts  = (int*)(wsb + aggr_bytes);
        int*   offsets = (int*)(wsb + aggr_bytes + cnt_bytes);
        int*   bsum    = (int*)(wsb + aggr_bytes + 2*cnt_bytes);
        int4*  rec     = (int4*)(wsb + base);

        (void)hipMemsetAsync(aggr, 0, aggr_bytes, stream);
        (void)hipMemsetAsync(counts, 0, cnt_bytes, stream);

        hist_kernel<<<tblocks, 256, 0, stream>>>(ei, counts, E);
        scan_partial<<<nsb, 256, 0, stream>>>(counts, bsum);
        scan_bsum<<<1, 256, 0, stream>>>(bsum, nsb);
        scan_emit<<<nsb, 256, 0, stream>>>(counts, bsum, offsets);
        scatter_kernel<<<tblocks, 256, 0, stream>>>(ei, offsets, rec, E);

        gine_edge_sorted<<<eblocks, 512, 0, stream>>>(x, ea, We, be, rec, aggr, E);
        gine_node<<<nblocks, 256, 0, stream>>>(x, aggr, epsp, W1, b1, bn_g, bn_b,
                                               bn_rm, bn_rv, W2, b2, ln_g, ln_b, out, N);
    } else {
        float* aggr = (ws_size >= aggr_bytes) ? (float*)d_ws : out;
        (void)hipMemsetAsync(aggr, 0, aggr_bytes, stream);
        gine_edge<<<eblocks, 256, 0, stream>>>(x, ei, ea, We, be, aggr, E);
        gine_node<<<nblocks, 256, 0, stream>>>(x, aggr, epsp, W1, b1, bn_g, bn_b,
                                               bn_rm, bn_rv, W2, b2, ln_g, ln_b, out, N);
    }
}